// Round 20
// baseline (472.450 us; speedup 1.0000x reference)
//
#include <hip/hip_runtime.h>
#include <hip/hip_bf16.h>
#include <cstdint>
#include <cstddef>

typedef __hip_bfloat16 bf16;
using short8 = __attribute__((ext_vector_type(8))) short;
using f32x4  = __attribute__((ext_vector_type(4))) float;
using float4v = __attribute__((ext_vector_type(4))) float;
using uint4v  = __attribute__((ext_vector_type(4))) unsigned int;

__device__ __forceinline__ float s2f(short s) {
  unsigned u = ((unsigned)(unsigned short)s) << 16;
  return __builtin_bit_cast(float, u);
}
__device__ __forceinline__ short f2s(float f) {  // RNE f32->bf16
  unsigned u = __builtin_bit_cast(unsigned, f);
  u += 0x7fffu + ((u >> 16) & 1u);
  return (short)(u >> 16);
}
__device__ __forceinline__ float bclo(unsigned u) { return __builtin_bit_cast(float, u << 16); }
__device__ __forceinline__ float bchi(unsigned u) { return __builtin_bit_cast(float, u & 0xFFFF0000u); }
__device__ __forceinline__ short bfbits(float f) {
  return __builtin_bit_cast(short, __float2bfloat16(f));
}

// ---------------- merged 1x1 conv + PReLU into zero-padded (+1 ring) f32 outputs ----
__global__ __launch_bounds__(256) void k_conv_all(
    const float* __restrict__ in_l, const float* __restrict__ in_s,
    const float* __restrict__ w_mlb, const float* __restrict__ b_mlb, const float* __restrict__ a_mlb,
    const float* __restrict__ w_m,   const float* __restrict__ b_m,   const float* __restrict__ a_m,
    const float* __restrict__ w_asm, const float* __restrict__ b_asm, const float* __restrict__ a_asm,
    float* __restrict__ MBpad, float* __restrict__ REFpad, float* __restrict__ BASEpad,
    int t1, int t2, int t3)
{
  int idx = blockIdx.x * 256 + threadIdx.x;
  const float *in, *w, *bi, *ap; float* o; int Cout, Hin, Win;
  if (idx < t1) { in = in_l; w = w_mlb; bi = b_mlb; ap = a_mlb; o = MBpad; Cout = 32; Hin = 96; Win = 96; }
  else if (idx < t1 + t2) { idx -= t1; in = in_s; w = w_m; bi = b_m; ap = a_m; o = REFpad; Cout = 32; Hin = 48; Win = 48; }
  else if (idx < t1 + t2 + t3) { idx -= t1 + t2; in = in_s; w = w_asm; bi = b_asm; ap = a_asm; o = BASEpad; Cout = 64; Hin = 48; Win = 48; }
  else return;
  int Wp = Win + 2, Hp = Hin + 2;
  int x = idx % Wp;
  int t = idx / Wp;
  int y = t % Hp; t /= Hp;
  int oc = t % Cout; int n = t / Cout;
  if (x == 0 || x == Wp - 1 || y == 0 || y == Hp - 1) { o[idx] = 0.0f; return; }
  int cs = Hin * Win;
  const float* ip = in + (size_t)n * 64 * cs + (size_t)(y - 1) * Win + (x - 1);
  const float* wp = w + oc * 64;
  float s = bi[oc];
#pragma unroll 16
  for (int ci = 0; ci < 64; ci++)
    s += wp[ci] * ip[(size_t)ci * cs];
  float a = ap[0];
  o[idx] = s >= 0.0f ? s : a * s;
}

// ---------------- merged gather/pack: Kp (stride 320) + Xp (stride 320) + Bb --------
__global__ __launch_bounds__(256) void k_gather_all(
    const float* __restrict__ mbpad, const float* __restrict__ refpad,
    const float* __restrict__ basepad,
    bf16* __restrict__ Kp, bf16* __restrict__ Xp, bf16* __restrict__ Bb)
{
  int b = blockIdx.x;
  int tid = threadIdx.x;
  if (b < 2304) {
    // key patches, L2-normalized, scale 10 folded; one wave per (n,l); stride 320
    int wid = b * 4 + (tid >> 6);
    int lane = tid & 63;
    int n = wid / 2304, l = wid % 2304, lh = l / 48, lw = l % 48;
    float v[5]; float ss = 0.f;
#pragma unroll
    for (int i = 0; i < 5; i++) {
      int k = lane + 64 * i; v[i] = 0.f;
      if (k < 288) {
        int c = k / 9, rr = (k % 9) / 3, sc = k % 3;
        v[i] = refpad[((size_t)(n * 32 + c) * 50 + lh + rr) * 50 + lw + sc];
        ss += v[i] * v[i];
      }
    }
#pragma unroll
    for (int off = 32; off; off >>= 1) ss += __shfl_xor(ss, off);
    float inv = 10.f / (sqrtf(ss) + 1e-4f);
#pragma unroll
    for (int i = 0; i < 5; i++) {
      int k = lane + 64 * i;
      Kp[(size_t)wid * 320 + k] = __float2bfloat16(k < 288 ? v[i] * inv : 0.f);
    }
  } else if (b < 2304 + 5760) {
    // query patches Xp[n][p][320], 8 bf16 per thread
    int idx = (b - 2304) * 256 + tid;        // (n,p,g) with g fastest
    int g = idx % 40;                         // 40 groups of 8 per 320-row
    int p = (idx / 40) % 9216;
    int n = idx / (40 * 9216);
    short8 v8 = (short8){0, 0, 0, 0, 0, 0, 0, 0};
    if (g < 36) {
      int ph = p / 96, pw = p % 96;
#pragma unroll
      for (int j = 0; j < 8; j++) {
        int k = g * 8 + j;
        int c = k / 9, rr = (k % 9) / 3, sc = k % 3;
        v8[j] = bfbits(mbpad[((size_t)(n * 32 + c) * 98 + ph + rr) * 98 + pw + sc]);
      }
    }
    *(short8*)((short*)Xp + (size_t)idx * 8) = v8;
  } else {
    // base value matrix Bb[n][o][l], 8 bf16 per thread (row-contiguous reads)
    int idx = (b - 2304 - 5760) * 256 + tid;  // (n,o,l8) with l8 fastest
    int l8 = idx % 288;
    int o = (idx / 288) % 64;
    int n = idx / (288 * 64);
    int l0 = l8 * 8;
    int lh = l0 / 48, lw = l0 % 48;
    const float* src = &basepad[((size_t)(n * 64 + o) * 50 + lh + 1) * 50 + lw + 1];
    short8 v8;
#pragma unroll
    for (int j = 0; j < 8; j++) v8[j] = bfbits(src[j]);
    *(short8*)((short*)Bb + (size_t)idx * 8) = v8;
  }
}

// ---------------- stage 1: QK tile GEMM + chunk-local softmax, writes P~ ------------
// block: 64q x 256l, 2x2 waves of 32q x 128l. 64-wide k-stages (frozen: BK=96
// doubled bank conflicts — round 14). Schedule: barrier A -> ds_write(pf) ->
// barrier B -> issue pf(s+1) -> compute(s) -> load xa(s+1) in place.
// blockIdx.z = sample-within-batch.
__global__ __launch_bounds__(256, 3) void k_qk(
    const bf16* __restrict__ Xp, const bf16* __restrict__ Kp,
    bf16* __restrict__ attnT, float* __restrict__ statsM, float* __restrict__ statsZ,
    int nbase, int qlo)
{
  __shared__ __align__(16) short KsPs[256 * 72];   // union: Ks 256x(64+8) / Ps 64x264
  __shared__ float Sm[2][2][32];
  __shared__ float Sz[2][2][32];
  int z = blockIdx.z;
  int n = nbase + z;
  attnT += (size_t)z * 9216 * 2304;      // batched mode: full-size per-sample rows
  statsM += (size_t)z * 9 * 9216;
  statsZ += (size_t)z * 9 * 9216;
  int tid = threadIdx.x, lane = tid & 63, wv = tid >> 6;
  int quad = lane >> 4, m16 = lane & 15;
  int wr = wv >> 1, wc = wv & 1;
  int q0 = qlo + blockIdx.x * 64;
  int l0 = blockIdx.y * 256;

  f32x4 acc[2][8];
#pragma unroll
  for (int mi = 0; mi < 2; mi++)
#pragma unroll
    for (int t = 0; t < 8; t++) acc[mi][t] = (f32x4){0.f, 0.f, 0.f, 0.f};

  const short* Xrow = (const short*)Xp + ((size_t)n * 9216 + q0 + wr * 32 + m16) * 320;
  const short* Ksrc = (const short*)Kp + ((size_t)n * 2304 + l0) * 320;
  int srow = tid >> 2;            // 0..63 (rows srow + 64p)
  int scol = (tid & 3) * 16;      // 0,16,32,48

  // prologue: stage-0 K loads, then stage-0 X fragments
  short8 pf[8];
#pragma unroll
  for (int p = 0; p < 4; p++)
#pragma unroll
    for (int v = 0; v < 2; v++)
      pf[p * 2 + v] = *(const short8*)&Ksrc[(size_t)(srow + 64 * p) * 320 + scol + v * 8];
  short8 xa0 = *(const short8*)&Xrow[quad * 8];
  short8 xa1 = *(const short8*)&Xrow[16 * 320 + quad * 8];
  short8 xa2 = *(const short8*)&Xrow[32 + quad * 8];
  short8 xa3 = *(const short8*)&Xrow[16 * 320 + 32 + quad * 8];

#pragma unroll
  for (int s = 0; s < 5; s++) {
    if (s) __syncthreads();       // (A) read->write hazard; drains pf(s)+xa(s)
#pragma unroll
    for (int p = 0; p < 4; p++)
#pragma unroll
      for (int v = 0; v < 2; v++)
        *(short8*)&KsPs[(srow + 64 * p) * 72 + scol + v * 8] = pf[p * 2 + v];
    __syncthreads();              // (B) write->read hazard
    if (s < 4) {
      int kn = (s + 1) * 64;
#pragma unroll
      for (int p = 0; p < 4; p++)
#pragma unroll
        for (int v = 0; v < 2; v++)
          pf[p * 2 + v] = *(const short8*)&Ksrc[(size_t)(srow + 64 * p) * 320 + kn + scol + v * 8];
    }
#pragma unroll
    for (int half = 0; half < 2; half++) {
      int kc = s * 64 + half * 32;
      if (kc >= 288) break;       // K=288; skip zero tail
      short8 a0 = half ? xa2 : xa0;
      short8 a1 = half ? xa3 : xa1;
#pragma unroll
      for (int t = 0; t < 8; t++) {
        short8 bfr = *(const short8*)&KsPs[(wc * 128 + t * 16 + m16) * 72 + half * 32 + quad * 8];
        acc[0][t] = __builtin_amdgcn_mfma_f32_16x16x32_bf16(a0, bfr, acc[0][t], 0, 0, 0);
        acc[1][t] = __builtin_amdgcn_mfma_f32_16x16x32_bf16(a1, bfr, acc[1][t], 0, 0, 0);
      }
    }
    if (s < 4) {                  // X fragments for stage s+1 (xa dead here)
      int kn = (s + 1) * 64;
      xa0 = *(const short8*)&Xrow[kn + quad * 8];
      xa1 = *(const short8*)&Xrow[16 * 320 + kn + quad * 8];
      xa2 = *(const short8*)&Xrow[kn + 32 + quad * 8];
      xa3 = *(const short8*)&Xrow[16 * 320 + kn + 32 + quad * 8];
    }
  }

  // local stats over this wave's 128 l
  float mloc[2][4], zloc[2][4], scale[2][4];
#pragma unroll
  for (int mi = 0; mi < 2; mi++)
#pragma unroll
    for (int r = 0; r < 4; r++) mloc[mi][r] = -3.0e38f;
#pragma unroll
  for (int mi = 0; mi < 2; mi++)
#pragma unroll
    for (int t = 0; t < 8; t++)
#pragma unroll
      for (int r = 0; r < 4; r++) mloc[mi][r] = fmaxf(mloc[mi][r], acc[mi][t][r]);
#pragma unroll
  for (int off = 1; off < 16; off <<= 1)
#pragma unroll
    for (int mi = 0; mi < 2; mi++)
#pragma unroll
      for (int r = 0; r < 4; r++) mloc[mi][r] = fmaxf(mloc[mi][r], __shfl_xor(mloc[mi][r], off));
#pragma unroll
  for (int mi = 0; mi < 2; mi++)
#pragma unroll
    for (int r = 0; r < 4; r++) zloc[mi][r] = 0.f;
#pragma unroll
  for (int mi = 0; mi < 2; mi++)
#pragma unroll
    for (int t = 0; t < 8; t++)
#pragma unroll
      for (int r = 0; r < 4; r++) {
        float e = __expf(acc[mi][t][r] - mloc[mi][r]);
        acc[mi][t][r] = e;
        zloc[mi][r] += e;
      }
#pragma unroll
  for (int off = 1; off < 16; off <<= 1)
#pragma unroll
    for (int mi = 0; mi < 2; mi++)
#pragma unroll
      for (int r = 0; r < 4; r++) zloc[mi][r] += __shfl_xor(zloc[mi][r], off);
  if (m16 == 0) {
#pragma unroll
    for (int mi = 0; mi < 2; mi++)
#pragma unroll
      for (int r = 0; r < 4; r++) {
        int qi = mi * 16 + quad * 4 + r;
        Sm[wc][wr][qi] = mloc[mi][r];
        Sz[wc][wr][qi] = zloc[mi][r];
      }
  }
  __syncthreads();   // stats visible; also guards Ks reuse as Ps below
#pragma unroll
  for (int mi = 0; mi < 2; mi++)
#pragma unroll
    for (int r = 0; r < 4; r++) {
      int qi = mi * 16 + quad * 4 + r;
      float mo = Sm[wc ^ 1][wr][qi];
      float zo = Sz[wc ^ 1][wr][qi];
      float mc = fmaxf(mloc[mi][r], mo);
      float sc = __expf(mloc[mi][r] - mc);
      scale[mi][r] = sc;
      if (m16 == 0 && wc == 0) {
        float zc = zloc[mi][r] * sc + zo * __expf(mo - mc);
        int qq = q0 + wr * 32 + qi;
        statsM[blockIdx.y * 9216 + qq] = mc;
        statsZ[blockIdx.y * 9216 + qq] = zc;
      }
    }
  // write P~ tile through LDS (coalesced global stores)
#pragma unroll
  for (int mi = 0; mi < 2; mi++)
#pragma unroll
    for (int t = 0; t < 8; t++)
#pragma unroll
      for (int r = 0; r < 4; r++)
        KsPs[(wr * 32 + mi * 16 + quad * 4 + r) * 264 + wc * 128 + t * 16 + m16] =
            f2s(acc[mi][t][r] * scale[mi][r]);
  __syncthreads();
  {
    int row = tid >> 2, part = tid & 3;
    short* dst = (short*)attnT + (size_t)(q0 - qlo + row) * 2304 + l0 + part * 64;
    const short* sp = &KsPs[row * 264 + part * 64];
#pragma unroll
    for (int v = 0; v < 8; v++)
      *(short8*)&dst[v * 8] = *(const short8*)&sp[v * 8];
  }
}

// ---------------- stage 2: combine chunk stats -> alpha[c][q] ----------------
// blockIdx.y = sample-within-batch.
__global__ __launch_bounds__(256) void k_alpha(
    const float* __restrict__ statsM, const float* __restrict__ statsZ,
    float* __restrict__ alpha, int qlo, int qlen)
{
  int z = blockIdx.y;
  statsM += (size_t)z * 9 * 9216;
  statsZ += (size_t)z * 9 * 9216;
  alpha  += (size_t)z * 9 * 9216;
  int i = blockIdx.x * 256 + threadIdx.x;
  if (i >= qlen) return;
  int q = qlo + i;
  float M = -3.0e38f;
#pragma unroll
  for (int c = 0; c < 9; c++) M = fmaxf(M, statsM[c * 9216 + q]);
  float Z = 0.f;
#pragma unroll
  for (int c = 0; c < 9; c++) Z += statsZ[c * 9216 + q] * __expf(statsM[c * 9216 + q] - M);
  float invZ = 1.f / Z;
#pragma unroll
  for (int c = 0; c < 9; c++) alpha[c * 9216 + q] = __expf(statsM[c * 9216 + q] - M) * invZ;
}

// ---- stage 3a: separable stencil, diagonal (dj) pass -------------------------------
// T[l,q] = sum_dj guard(w,lw0,dj) * P~[l+dj, q+dj] * alpha[chunk][q+dj]
// (the di=0 bank of the old 9-tap kernel, verbatim). Loads unconditional
// (workspace-interior); FMAs guarded. T (bf16) -> Tbuf. blockIdx.z = sample.
__global__ __launch_bounds__(256) void k_a2v(
    const bf16* __restrict__ attnT, const float* __restrict__ alpha,
    bf16* __restrict__ T, int qlo)
{
  int z = blockIdx.z;
  attnT += (size_t)z * 9216 * 2304;
  alpha += (size_t)z * 9 * 9216;
  T     += (size_t)z * 9216 * 2304;
  int bpx = gridDim.x >> 3;
  int nb = (blockIdx.x & 7) * bpx + (blockIdx.x >> 3);
  int g = nb * 256 + threadIdx.x;
  int qrel = g / 144;                 // row within band
  int j = g - qrel * 144;
  int l0 = j * 16;
  int q = qlo + qrel;
  int w = q % 96;
  int lw0 = l0 % 48;                  // 0,16,32
  int c0 = l0 >> 8;
  const short* r0 = (const short*)attnT + (size_t)qrel * 2304 + l0;
  const float* alc = alpha + c0 * 9216;

  // straight-line loads (all in flight)
  uint4v Va = *(const uint4v*)(r0);
  uint4v Vb = *(const uint4v*)(r0 + 8);
  unsigned Pw = *(const unsigned*)(r0 - 2304 - 2);
  uint4v Ma = *(const uint4v*)(r0 - 2304);
  uint4v Mb = *(const uint4v*)(r0 - 2304 + 8);
  uint4v Pa = *(const uint4v*)(r0 + 2304);
  uint4v Pb = *(const uint4v*)(r0 + 2304 + 8);
  unsigned Nw = *(const unsigned*)(r0 + 2304 + 16);
  float a  = alc[q];
  float am = alc[q - 1];
  float ap = alc[q + 1];

  float acc[16];
  { // dj = 0
#pragma unroll
    for (int k = 0; k < 4; k++) {
      acc[2 * k]      = bclo(Va[k]) * a;  acc[2 * k + 1]  = bchi(Va[k]) * a;
      acc[8 + 2 * k]  = bclo(Vb[k]) * a;  acc[9 + 2 * k]  = bchi(Vb[k]) * a;
    }
  }
  if (w > 0) { // dj = -1: shorts [l0-1 .. l0+14] of row q-1; elem0 may be chunk c0-1
    float a0 = ((l0 & 255) == 0 && c0 > 0) ? alpha[(c0 - 1) * 9216 + q - 1] : am;
    unsigned D[8] = { Ma[0], Ma[1], Ma[2], Ma[3], Mb[0], Mb[1], Mb[2], Mb[3] };
    unsigned E0 = (Pw >> 16) | (D[0] << 16);
    if (lw0 == 0) E0 &= 0xFFFF0000u;     // elem0 would wrap to prev lh row
    acc[0] += bclo(E0) * a0;  acc[1] += bchi(E0) * am;
#pragma unroll
    for (int k = 1; k < 8; k++) {
      unsigned Ek = (D[k - 1] >> 16) | (D[k] << 16);
      acc[2 * k] += bclo(Ek) * am;  acc[2 * k + 1] += bchi(Ek) * am;
    }
  }
  if (w < 95) { // dj = +1: shorts [l0+1 .. l0+16] of row q+1; elem15 may be chunk c0+1
    float a15 = ((l0 & 255) == 240 && c0 < 8) ? alpha[(c0 + 1) * 9216 + q + 1] : ap;
    unsigned D[9] = { Pa[0], Pa[1], Pa[2], Pa[3], Pb[0], Pb[1], Pb[2], Pb[3], Nw };
    unsigned F7 = (D[7] >> 16) | (D[8] << 16);
    if (lw0 == 32) F7 &= 0x0000FFFFu;    // elem15 would wrap to next lh row
#pragma unroll
    for (int k = 0; k < 7; k++) {
      unsigned Fk = (D[k] >> 16) | (D[k + 1] << 16);
      acc[2 * k] += bclo(Fk) * ap;  acc[2 * k + 1] += bchi(Fk) * ap;
    }
    acc[14] += bclo(F7) * ap;  acc[15] += bchi(F7) * a15;
  }

  short8 o0, o1;
#pragma unroll
  for (int k = 0; k < 8; k++) { o0[k] = f2s(acc[k]); o1[k] = f2s(acc[8 + k]); }
  short* dst = (short*)T + (size_t)qrel * 2304 + l0;
  *(short8*)dst = o0;
  *(short8*)(dst + 8) = o1;
}

// ---- stage 4: PV GEMM with FUSED coarse (di) stencil pass, direct epilogue ---------
// A-operand built in-register from T: 3 aligned 16B taps (c, ±(96 rows, 48 cols)) +
// guarded f32 adds in a2u's exact u order + same f2s -> bit-identical MFMA inputs.
// XCD-chunked q mapping. ROUND 20: the y=2 k-split removed — round 18's counters
// showed pv3 occupancy is VGPR/LDS-limited (~2.7 blocks/CU resident), NOT
// grid-limited (1152 blocks >> ~690 resident), so one partition keeps every CU
// equally busy while eliminating the Ppart round-trip (57 MB/pair) and the k_comb
// dispatch. 4 waves each own 576 of K=2304 (the original round-8..18 partition ->
// same accumulation order), LDS reduction, direct out = inl + 0.25*s float4 stores
// (disjoint, no atomics). blockIdx.z = sample-within-batch.
__global__ __launch_bounds__(256) void k_pv3(
    const bf16* __restrict__ T, const bf16* __restrict__ Bb,
    const float* __restrict__ inl, float* __restrict__ out,
    int nbase, int q0base, int qlo)
{
  __shared__ float Cred[4][16][67];
  int z = blockIdx.z;
  int n = nbase + z;
  T += (size_t)z * 9216 * 2304;
  int bpx = gridDim.x >> 3;
  int nb = (blockIdx.x & 7) * bpx + (blockIdx.x >> 3);   // XCD-chunked q mapping
  int tid = threadIdx.x, lane = tid & 63, wv = tid >> 6;
  int quad = lane >> 4, m16 = lane & 15;
  int qb = nb * 16;
  int kbase = wv * 576;
  int q = q0base + qb + m16;          // absolute query row this lane owns
  int h = q / 96;
  const short* Trow = (const short*)T + (size_t)(q - qlo) * 2304;
  const short* Bp = (const short*)Bb + (size_t)n * 64 * 2304 + kbase;
  f32x4 acc[4];
#pragma unroll
  for (int t = 0; t < 4; t++) acc[t] = (f32x4){0.f, 0.f, 0.f, 0.f};

  // depth-1 double-buffered taps + B fragments ([2] arrays, static indexing)
  uint4v Ct[2], Nt[2], Pt[2];
  short8 bt[2][4];
  {
    const short* tc0 = Trow + kbase + quad * 8;
    Ct[0] = *(const uint4v*)(tc0);
    Nt[0] = *(const uint4v*)(tc0 - (size_t)96 * 2304 - 48);
    Pt[0] = *(const uint4v*)(tc0 + (size_t)96 * 2304 + 48);
#pragma unroll
    for (int ni = 0; ni < 4; ni++)
      bt[0][ni] = *(const short8*)&Bp[(size_t)(ni * 16 + m16) * 2304 + quad * 8];
  }

#pragma unroll
  for (int it = 0; it < 18; it++) {
    int cur = it & 1, nxt = cur ^ 1;
    if (it < 17) {                     // issue next iteration's loads first
      int kw1 = (it + 1) * 32;
      const short* tc1 = Trow + kbase + kw1 + quad * 8;
      Ct[nxt] = *(const uint4v*)(tc1);
      Nt[nxt] = *(const uint4v*)(tc1 - (size_t)96 * 2304 - 48);
      Pt[nxt] = *(const uint4v*)(tc1 + (size_t)96 * 2304 + 48);
#pragma unroll
      for (int ni = 0; ni < 4; ni++)
        bt[nxt][ni] = *(const short8*)&Bp[(size_t)(ni * 16 + m16) * 2304 + kw1 + quad * 8];
    }
    int labs = kbase + it * 32 + quad * 8;  // absolute l of this lane's 8-col A group
    int lh = labs / 48;                     // 0..47
    float s[8];
#pragma unroll
    for (int k = 0; k < 8; k++) s[k] = 0.f;
    if (h > 0 && lh > 0) {             // u = -1
#pragma unroll
      for (int k = 0; k < 4; k++) { s[2 * k] += bclo(Nt[cur][k]); s[2 * k + 1] += bchi(Nt[cur][k]); }
    }
    {                                  // u = 0
#pragma unroll
      for (int k = 0; k < 4; k++) { s[2 * k] += bclo(Ct[cur][k]); s[2 * k + 1] += bchi(Ct[cur][k]); }
    }
    if (h < 95 && lh < 47) {           // u = +1
#pragma unroll
      for (int k = 0; k < 4; k++) { s[2 * k] += bclo(Pt[cur][k]); s[2 * k + 1] += bchi(Pt[cur][k]); }
    }
    short8 a;
#pragma unroll
    for (int k = 0; k < 8; k++) a[k] = f2s(s[k]);
#pragma unroll
    for (int ni = 0; ni < 4; ni++)
      acc[ni] = __builtin_amdgcn_mfma_f32_16x16x32_bf16(a, bt[cur][ni], acc[ni], 0, 0, 0);
  }
#pragma unroll
  for (int ni = 0; ni < 4; ni++)
#pragma unroll
    for (int r = 0; r < 4; r++)
      Cred[wv][quad * 4 + r][ni * 16 + m16] = acc[ni][r];
  __syncthreads();
  {
    int o = tid >> 2;                // 0..63
    int qg = (tid & 3) * 4;          // 0..12
    size_t oid = ((size_t)(n * 64 + o)) * 9216 + q0base + qb + qg;
    float4v s;
#pragma unroll
    for (int j = 0; j < 4; j++)
      s[j] = Cred[0][qg + j][o] + Cred[1][qg + j][o] + Cred[2][qg + j][o] + Cred[3][qg + j][o];
    float4v rv = *(const float4v*)&inl[oid];
    float4v y;
#pragma unroll
    for (int j = 0; j < 4; j++) y[j] = rv[j] + 0.25f * s[j];
    *(float4v*)&out[oid] = y;
  }
}

extern "C" void kernel_launch(void* const* d_in, const int* in_sizes, int n_in,
                              void* d_out, int out_size, void* d_ws, size_t ws_size,
                              hipStream_t stream)
{
  (void)in_sizes; (void)n_in; (void)out_size;
  const float* input_l = (const float*)d_in[0];
  const float* input_s = (const float*)d_in[1];
  const float* w_mlb = (const float*)d_in[2];
  const float* b_mlb = (const float*)d_in[3];
  const float* a_mlb = (const float*)d_in[4];
  const float* w_m   = (const float*)d_in[5];
  const float* b_m   = (const float*)d_in[6];
  const float* a_m   = (const float*)d_in[7];
  const float* w_asm = (const float*)d_in[8];
  const float* b_asm = (const float*)d_in[9];
  const float* a_asm = (const float*)d_in[10];
  float* out = (float*)d_out;

  char* base = (char*)d_ws;
  size_t off = 0;
  auto carve = [&](size_t bytes) -> char* {
    char* r = base + off;
    off += (bytes + 255) & ~(size_t)255;
    return r;
  };

  float* MBpad   = (float*)carve((size_t)4 * 32 * 98 * 98 * 4);
  float* REFpad  = (float*)carve((size_t)4 * 32 * 50 * 50 * 4);
  float* BASEpad = (float*)carve((size_t)4 * 64 * 50 * 50 * 4);
  bf16*  Kp      = (bf16*)carve((size_t)4 * 2304 * 320 * 2);
  bf16*  Xp      = (bf16*)carve((size_t)4 * 9216 * 320 * 2);
  bf16*  Bb      = (bf16*)carve((size_t)4 * 64 * 2304 * 2);
  float* statsM  = (float*)carve((size_t)2 * 9 * 9216 * 4);   // x2 for paired batch
  float* statsZ  = (float*)carve((size_t)2 * 9 * 9216 * 4);
  float* alpha   = (float*)carve((size_t)2 * 9 * 9216 * 4);
  size_t fixedOff = off;

  auto need = [&](int qmax, int B) -> size_t {
    size_t a = (((size_t)qmax * 2304 * 2) * B + 255) & ~(size_t)255;
    return fixedOff + 2 * a;   // attnT + T, both qmax-sized
  };
  int nsplit, qmax, psplit, batchB;
  if (need(9216, 2) <= ws_size)      { batchB = 2; nsplit = 1; qmax = 9216; psplit = 9216; }
  else if (need(9216, 1) <= ws_size) { batchB = 1; nsplit = 1; qmax = 9216; psplit = 9216; }
  else if (need(5120, 1) <= ws_size) { batchB = 1; nsplit = 2; qmax = 5120; psplit = 4608; }
  else                               { batchB = 1; nsplit = 4; qmax = 2816; psplit = 2304; }

  bf16* attnT = (bf16*)carve((size_t)qmax * 2304 * 2 * batchB);
  bf16* Tbuf  = (bf16*)carve((size_t)qmax * 2304 * 2 * batchB);

  // ---- prep (all samples, 2 dispatches) ----
  {
    int t1 = 4 * 32 * 98 * 98;
    int t2 = 4 * 32 * 50 * 50;
    int t3 = 4 * 64 * 50 * 50;
    int tt = t1 + t2 + t3;
    k_conv_all<<<dim3((tt + 255) / 256), dim3(256), 0, stream>>>(
        input_l, input_s, w_mlb, b_mlb, a_mlb, w_m, b_m, a_m, w_asm, b_asm, a_asm,
        MBpad, REFpad, BASEpad, t1, t2, t3);
    k_gather_all<<<dim3(2304 + 5760 + 288), dim3(256), 0, stream>>>(
        MBpad, REFpad, BASEpad, Kp, Xp, Bb);
  }

  if (batchB == 2) {
    // ---- paired-sample batching ----
    for (int p = 0; p < 2; p++) {
      int nb = p * 2;
      k_qk<<<dim3(144, 9, 2), dim3(256), 0, stream>>>(Xp, Kp, attnT, statsM, statsZ, nb, 0);
      k_alpha<<<dim3(36, 2), dim3(256), 0, stream>>>(statsM, statsZ, alpha, 0, 9216);
      k_a2v<<<dim3(5184, 1, 2), dim3(256), 0, stream>>>(attnT, alpha, Tbuf, 0);
      k_pv3<<<dim3(576, 1, 2), dim3(256), 0, stream>>>(Tbuf, Bb, input_l, out, nb, 0, 0);
    }
  } else {
    // ---- fallback: per (sample, query band), z = 0 everywhere ----
    for (int n = 0; n < 4; n++) {
      for (int s = 0; s < nsplit; s++) {
        int q0 = s * psplit;
        int qlo = q0 - 256; if (qlo < 0) qlo = 0;
        int qhi = q0 + psplit + 256; if (qhi > 9216) qhi = 9216;
        int qlen = qhi - qlo;  // multiple of 256 by construction
        k_qk<<<dim3(qlen / 64, 9, 1), dim3(256), 0, stream>>>(Xp, Kp, attnT, statsM, statsZ, n, qlo);
        k_alpha<<<dim3(qlen / 256, 1), dim3(256), 0, stream>>>(statsM, statsZ, alpha, qlo, qlen);
        k_a2v<<<dim3(qlen * 144 / 256, 1, 1), dim3(256), 0, stream>>>(attnT, alpha, Tbuf, qlo);
        k_pv3<<<dim3(psplit / 16, 1, 1), dim3(256), 0, stream>>>(Tbuf, Bb, input_l, out, n, q0, qlo);
      }
    }
  }
}

// Round 21
// 463.610 us; speedup vs baseline: 1.0191x; 1.0191x over previous
//
#include <hip/hip_runtime.h>
#include <hip/hip_bf16.h>
#include <cstdint>
#include <cstddef>

typedef __hip_bfloat16 bf16;
using short8 = __attribute__((ext_vector_type(8))) short;
using f32x4  = __attribute__((ext_vector_type(4))) float;
using float4v = __attribute__((ext_vector_type(4))) float;
using uint4v  = __attribute__((ext_vector_type(4))) unsigned int;

__device__ __forceinline__ float s2f(short s) {
  unsigned u = ((unsigned)(unsigned short)s) << 16;
  return __builtin_bit_cast(float, u);
}
__device__ __forceinline__ short f2s(float f) {  // RNE f32->bf16
  unsigned u = __builtin_bit_cast(unsigned, f);
  u += 0x7fffu + ((u >> 16) & 1u);
  return (short)(u >> 16);
}
__device__ __forceinline__ float bclo(unsigned u) { return __builtin_bit_cast(float, u << 16); }
__device__ __forceinline__ float bchi(unsigned u) { return __builtin_bit_cast(float, u & 0xFFFF0000u); }
__device__ __forceinline__ short bfbits(float f) {
  return __builtin_bit_cast(short, __float2bfloat16(f));
}

// ---------------- merged 1x1 conv + PReLU into zero-padded (+1 ring) f32 outputs ----
__global__ __launch_bounds__(256) void k_conv_all(
    const float* __restrict__ in_l, const float* __restrict__ in_s,
    const float* __restrict__ w_mlb, const float* __restrict__ b_mlb, const float* __restrict__ a_mlb,
    const float* __restrict__ w_m,   const float* __restrict__ b_m,   const float* __restrict__ a_m,
    const float* __restrict__ w_asm, const float* __restrict__ b_asm, const float* __restrict__ a_asm,
    float* __restrict__ MBpad, float* __restrict__ REFpad, float* __restrict__ BASEpad,
    int t1, int t2, int t3)
{
  int idx = blockIdx.x * 256 + threadIdx.x;
  const float *in, *w, *bi, *ap; float* o; int Cout, Hin, Win;
  if (idx < t1) { in = in_l; w = w_mlb; bi = b_mlb; ap = a_mlb; o = MBpad; Cout = 32; Hin = 96; Win = 96; }
  else if (idx < t1 + t2) { idx -= t1; in = in_s; w = w_m; bi = b_m; ap = a_m; o = REFpad; Cout = 32; Hin = 48; Win = 48; }
  else if (idx < t1 + t2 + t3) { idx -= t1 + t2; in = in_s; w = w_asm; bi = b_asm; ap = a_asm; o = BASEpad; Cout = 64; Hin = 48; Win = 48; }
  else return;
  int Wp = Win + 2, Hp = Hin + 2;
  int x = idx % Wp;
  int t = idx / Wp;
  int y = t % Hp; t /= Hp;
  int oc = t % Cout; int n = t / Cout;
  if (x == 0 || x == Wp - 1 || y == 0 || y == Hp - 1) { o[idx] = 0.0f; return; }
  int cs = Hin * Win;
  const float* ip = in + (size_t)n * 64 * cs + (size_t)(y - 1) * Win + (x - 1);
  const float* wp = w + oc * 64;
  float s = bi[oc];
#pragma unroll 16
  for (int ci = 0; ci < 64; ci++)
    s += wp[ci] * ip[(size_t)ci * cs];
  float a = ap[0];
  o[idx] = s >= 0.0f ? s : a * s;
}

// ---------------- merged gather/pack: Kp (stride 320) + Xp (stride 320) + Bb --------
__global__ __launch_bounds__(256) void k_gather_all(
    const float* __restrict__ mbpad, const float* __restrict__ refpad,
    const float* __restrict__ basepad,
    bf16* __restrict__ Kp, bf16* __restrict__ Xp, bf16* __restrict__ Bb)
{
  int b = blockIdx.x;
  int tid = threadIdx.x;
  if (b < 2304) {
    // key patches, L2-normalized, scale 10 folded; one wave per (n,l); stride 320
    int wid = b * 4 + (tid >> 6);
    int lane = tid & 63;
    int n = wid / 2304, l = wid % 2304, lh = l / 48, lw = l % 48;
    float v[5]; float ss = 0.f;
#pragma unroll
    for (int i = 0; i < 5; i++) {
      int k = lane + 64 * i; v[i] = 0.f;
      if (k < 288) {
        int c = k / 9, rr = (k % 9) / 3, sc = k % 3;
        v[i] = refpad[((size_t)(n * 32 + c) * 50 + lh + rr) * 50 + lw + sc];
        ss += v[i] * v[i];
      }
    }
#pragma unroll
    for (int off = 32; off; off >>= 1) ss += __shfl_xor(ss, off);
    float inv = 10.f / (sqrtf(ss) + 1e-4f);
#pragma unroll
    for (int i = 0; i < 5; i++) {
      int k = lane + 64 * i;
      Kp[(size_t)wid * 320 + k] = __float2bfloat16(k < 288 ? v[i] * inv : 0.f);
    }
  } else if (b < 2304 + 5760) {
    // query patches Xp[n][p][320], 8 bf16 per thread
    int idx = (b - 2304) * 256 + tid;        // (n,p,g) with g fastest
    int g = idx % 40;                         // 40 groups of 8 per 320-row
    int p = (idx / 40) % 9216;
    int n = idx / (40 * 9216);
    short8 v8 = (short8){0, 0, 0, 0, 0, 0, 0, 0};
    if (g < 36) {
      int ph = p / 96, pw = p % 96;
#pragma unroll
      for (int j = 0; j < 8; j++) {
        int k = g * 8 + j;
        int c = k / 9, rr = (k % 9) / 3, sc = k % 3;
        v8[j] = bfbits(mbpad[((size_t)(n * 32 + c) * 98 + ph + rr) * 98 + pw + sc]);
      }
    }
    *(short8*)((short*)Xp + (size_t)idx * 8) = v8;
  } else {
    // base value matrix Bb[n][o][l], 8 bf16 per thread (row-contiguous reads)
    int idx = (b - 2304 - 5760) * 256 + tid;  // (n,o,l8) with l8 fastest
    int l8 = idx % 288;
    int o = (idx / 288) % 64;
    int n = idx / (288 * 64);
    int l0 = l8 * 8;
    int lh = l0 / 48, lw = l0 % 48;
    const float* src = &basepad[((size_t)(n * 64 + o) * 50 + lh + 1) * 50 + lw + 1];
    short8 v8;
#pragma unroll
    for (int j = 0; j < 8; j++) v8[j] = bfbits(src[j]);
    *(short8*)((short*)Bb + (size_t)idx * 8) = v8;
  }
}

// ---------------- stage 1: QK tile GEMM + chunk-local softmax, writes P~ ------------
// block: 64q x 256l, 2x2 waves of 32q x 128l. 64-wide k-stages (frozen: BK=96
// doubled bank conflicts — round 14). Schedule: barrier A -> ds_write(pf) ->
// barrier B -> issue pf(s+1) -> compute(s) -> load xa(s+1) in place.
// blockIdx.z = sample-within-batch.
__global__ __launch_bounds__(256, 3) void k_qk(
    const bf16* __restrict__ Xp, const bf16* __restrict__ Kp,
    bf16* __restrict__ attnT, float* __restrict__ statsM, float* __restrict__ statsZ,
    int nbase, int qlo)
{
  __shared__ __align__(16) short KsPs[256 * 72];   // union: Ks 256x(64+8) / Ps 64x264
  __shared__ float Sm[2][2][32];
  __shared__ float Sz[2][2][32];
  int z = blockIdx.z;
  int n = nbase + z;
  attnT += (size_t)z * 9216 * 2304;      // batched mode: full-size per-sample rows
  statsM += (size_t)z * 9 * 9216;
  statsZ += (size_t)z * 9 * 9216;
  int tid = threadIdx.x, lane = tid & 63, wv = tid >> 6;
  int quad = lane >> 4, m16 = lane & 15;
  int wr = wv >> 1, wc = wv & 1;
  int q0 = qlo + blockIdx.x * 64;
  int l0 = blockIdx.y * 256;

  f32x4 acc[2][8];
#pragma unroll
  for (int mi = 0; mi < 2; mi++)
#pragma unroll
    for (int t = 0; t < 8; t++) acc[mi][t] = (f32x4){0.f, 0.f, 0.f, 0.f};

  const short* Xrow = (const short*)Xp + ((size_t)n * 9216 + q0 + wr * 32 + m16) * 320;
  const short* Ksrc = (const short*)Kp + ((size_t)n * 2304 + l0) * 320;
  int srow = tid >> 2;            // 0..63 (rows srow + 64p)
  int scol = (tid & 3) * 16;      // 0,16,32,48

  // prologue: stage-0 K loads, then stage-0 X fragments
  short8 pf[8];
#pragma unroll
  for (int p = 0; p < 4; p++)
#pragma unroll
    for (int v = 0; v < 2; v++)
      pf[p * 2 + v] = *(const short8*)&Ksrc[(size_t)(srow + 64 * p) * 320 + scol + v * 8];
  short8 xa0 = *(const short8*)&Xrow[quad * 8];
  short8 xa1 = *(const short8*)&Xrow[16 * 320 + quad * 8];
  short8 xa2 = *(const short8*)&Xrow[32 + quad * 8];
  short8 xa3 = *(const short8*)&Xrow[16 * 320 + 32 + quad * 8];

#pragma unroll
  for (int s = 0; s < 5; s++) {
    if (s) __syncthreads();       // (A) read->write hazard; drains pf(s)+xa(s)
#pragma unroll
    for (int p = 0; p < 4; p++)
#pragma unroll
      for (int v = 0; v < 2; v++)
        *(short8*)&KsPs[(srow + 64 * p) * 72 + scol + v * 8] = pf[p * 2 + v];
    __syncthreads();              // (B) write->read hazard
    if (s < 4) {
      int kn = (s + 1) * 64;
#pragma unroll
      for (int p = 0; p < 4; p++)
#pragma unroll
        for (int v = 0; v < 2; v++)
          pf[p * 2 + v] = *(const short8*)&Ksrc[(size_t)(srow + 64 * p) * 320 + kn + scol + v * 8];
    }
#pragma unroll
    for (int half = 0; half < 2; half++) {
      int kc = s * 64 + half * 32;
      if (kc >= 288) break;       // K=288; skip zero tail
      short8 a0 = half ? xa2 : xa0;
      short8 a1 = half ? xa3 : xa1;
#pragma unroll
      for (int t = 0; t < 8; t++) {
        short8 bfr = *(const short8*)&KsPs[(wc * 128 + t * 16 + m16) * 72 + half * 32 + quad * 8];
        acc[0][t] = __builtin_amdgcn_mfma_f32_16x16x32_bf16(a0, bfr, acc[0][t], 0, 0, 0);
        acc[1][t] = __builtin_amdgcn_mfma_f32_16x16x32_bf16(a1, bfr, acc[1][t], 0, 0, 0);
      }
    }
    if (s < 4) {                  // X fragments for stage s+1 (xa dead here)
      int kn = (s + 1) * 64;
      xa0 = *(const short8*)&Xrow[kn + quad * 8];
      xa1 = *(const short8*)&Xrow[16 * 320 + kn + quad * 8];
      xa2 = *(const short8*)&Xrow[kn + 32 + quad * 8];
      xa3 = *(const short8*)&Xrow[16 * 320 + kn + 32 + quad * 8];
    }
  }

  // local stats over this wave's 128 l
  float mloc[2][4], zloc[2][4], scale[2][4];
#pragma unroll
  for (int mi = 0; mi < 2; mi++)
#pragma unroll
    for (int r = 0; r < 4; r++) mloc[mi][r] = -3.0e38f;
#pragma unroll
  for (int mi = 0; mi < 2; mi++)
#pragma unroll
    for (int t = 0; t < 8; t++)
#pragma unroll
      for (int r = 0; r < 4; r++) mloc[mi][r] = fmaxf(mloc[mi][r], acc[mi][t][r]);
#pragma unroll
  for (int off = 1; off < 16; off <<= 1)
#pragma unroll
    for (int mi = 0; mi < 2; mi++)
#pragma unroll
      for (int r = 0; r < 4; r++) mloc[mi][r] = fmaxf(mloc[mi][r], __shfl_xor(mloc[mi][r], off));
#pragma unroll
  for (int mi = 0; mi < 2; mi++)
#pragma unroll
    for (int r = 0; r < 4; r++) zloc[mi][r] = 0.f;
#pragma unroll
  for (int mi = 0; mi < 2; mi++)
#pragma unroll
    for (int t = 0; t < 8; t++)
#pragma unroll
      for (int r = 0; r < 4; r++) {
        float e = __expf(acc[mi][t][r] - mloc[mi][r]);
        acc[mi][t][r] = e;
        zloc[mi][r] += e;
      }
#pragma unroll
  for (int off = 1; off < 16; off <<= 1)
#pragma unroll
    for (int mi = 0; mi < 2; mi++)
#pragma unroll
      for (int r = 0; r < 4; r++) zloc[mi][r] += __shfl_xor(zloc[mi][r], off);
  if (m16 == 0) {
#pragma unroll
    for (int mi = 0; mi < 2; mi++)
#pragma unroll
      for (int r = 0; r < 4; r++) {
        int qi = mi * 16 + quad * 4 + r;
        Sm[wc][wr][qi] = mloc[mi][r];
        Sz[wc][wr][qi] = zloc[mi][r];
      }
  }
  __syncthreads();   // stats visible; also guards Ks reuse as Ps below
#pragma unroll
  for (int mi = 0; mi < 2; mi++)
#pragma unroll
    for (int r = 0; r < 4; r++) {
      int qi = mi * 16 + quad * 4 + r;
      float mo = Sm[wc ^ 1][wr][qi];
      float zo = Sz[wc ^ 1][wr][qi];
      float mc = fmaxf(mloc[mi][r], mo);
      float sc = __expf(mloc[mi][r] - mc);
      scale[mi][r] = sc;
      if (m16 == 0 && wc == 0) {
        float zc = zloc[mi][r] * sc + zo * __expf(mo - mc);
        int qq = q0 + wr * 32 + qi;
        statsM[blockIdx.y * 9216 + qq] = mc;
        statsZ[blockIdx.y * 9216 + qq] = zc;
      }
    }
  // write P~ tile through LDS (coalesced global stores)
#pragma unroll
  for (int mi = 0; mi < 2; mi++)
#pragma unroll
    for (int t = 0; t < 8; t++)
#pragma unroll
      for (int r = 0; r < 4; r++)
        KsPs[(wr * 32 + mi * 16 + quad * 4 + r) * 264 + wc * 128 + t * 16 + m16] =
            f2s(acc[mi][t][r] * scale[mi][r]);
  __syncthreads();
  {
    int row = tid >> 2, part = tid & 3;
    short* dst = (short*)attnT + (size_t)(q0 - qlo + row) * 2304 + l0 + part * 64;
    const short* sp = &KsPs[row * 264 + part * 64];
#pragma unroll
    for (int v = 0; v < 8; v++)
      *(short8*)&dst[v * 8] = *(const short8*)&sp[v * 8];
  }
}

// ---------------- stage 2: combine chunk stats -> alpha[c][q] ----------------
// blockIdx.y = sample-within-batch.
__global__ __launch_bounds__(256) void k_alpha(
    const float* __restrict__ statsM, const float* __restrict__ statsZ,
    float* __restrict__ alpha, int qlo, int qlen)
{
  int z = blockIdx.y;
  statsM += (size_t)z * 9 * 9216;
  statsZ += (size_t)z * 9 * 9216;
  alpha  += (size_t)z * 9 * 9216;
  int i = blockIdx.x * 256 + threadIdx.x;
  if (i >= qlen) return;
  int q = qlo + i;
  float M = -3.0e38f;
#pragma unroll
  for (int c = 0; c < 9; c++) M = fmaxf(M, statsM[c * 9216 + q]);
  float Z = 0.f;
#pragma unroll
  for (int c = 0; c < 9; c++) Z += statsZ[c * 9216 + q] * __expf(statsM[c * 9216 + q] - M);
  float invZ = 1.f / Z;
#pragma unroll
  for (int c = 0; c < 9; c++) alpha[c * 9216 + q] = __expf(statsM[c * 9216 + q] - M) * invZ;
}

// ---- stage 3a: separable stencil, diagonal (dj) pass -------------------------------
// T[l,q] = sum_dj guard(w,lw0,dj) * P~[l+dj, q+dj] * alpha[chunk][q+dj]
// (the di=0 bank of the old 9-tap kernel, verbatim). Loads unconditional
// (workspace-interior); FMAs guarded. T (bf16) -> Tbuf. blockIdx.z = sample.
__global__ __launch_bounds__(256) void k_a2v(
    const bf16* __restrict__ attnT, const float* __restrict__ alpha,
    bf16* __restrict__ T, int qlo)
{
  int z = blockIdx.z;
  attnT += (size_t)z * 9216 * 2304;
  alpha += (size_t)z * 9 * 9216;
  T     += (size_t)z * 9216 * 2304;
  int bpx = gridDim.x >> 3;
  int nb = (blockIdx.x & 7) * bpx + (blockIdx.x >> 3);
  int g = nb * 256 + threadIdx.x;
  int qrel = g / 144;                 // row within band
  int j = g - qrel * 144;
  int l0 = j * 16;
  int q = qlo + qrel;
  int w = q % 96;
  int lw0 = l0 % 48;                  // 0,16,32
  int c0 = l0 >> 8;
  const short* r0 = (const short*)attnT + (size_t)qrel * 2304 + l0;
  const float* alc = alpha + c0 * 9216;

  // straight-line loads (all in flight)
  uint4v Va = *(const uint4v*)(r0);
  uint4v Vb = *(const uint4v*)(r0 + 8);
  unsigned Pw = *(const unsigned*)(r0 - 2304 - 2);
  uint4v Ma = *(const uint4v*)(r0 - 2304);
  uint4v Mb = *(const uint4v*)(r0 - 2304 + 8);
  uint4v Pa = *(const uint4v*)(r0 + 2304);
  uint4v Pb = *(const uint4v*)(r0 + 2304 + 8);
  unsigned Nw = *(const unsigned*)(r0 + 2304 + 16);
  float a  = alc[q];
  float am = alc[q - 1];
  float ap = alc[q + 1];

  float acc[16];
  { // dj = 0
#pragma unroll
    for (int k = 0; k < 4; k++) {
      acc[2 * k]      = bclo(Va[k]) * a;  acc[2 * k + 1]  = bchi(Va[k]) * a;
      acc[8 + 2 * k]  = bclo(Vb[k]) * a;  acc[9 + 2 * k]  = bchi(Vb[k]) * a;
    }
  }
  if (w > 0) { // dj = -1: shorts [l0-1 .. l0+14] of row q-1; elem0 may be chunk c0-1
    float a0 = ((l0 & 255) == 0 && c0 > 0) ? alpha[(c0 - 1) * 9216 + q - 1] : am;
    unsigned D[8] = { Ma[0], Ma[1], Ma[2], Ma[3], Mb[0], Mb[1], Mb[2], Mb[3] };
    unsigned E0 = (Pw >> 16) | (D[0] << 16);
    if (lw0 == 0) E0 &= 0xFFFF0000u;     // elem0 would wrap to prev lh row
    acc[0] += bclo(E0) * a0;  acc[1] += bchi(E0) * am;
#pragma unroll
    for (int k = 1; k < 8; k++) {
      unsigned Ek = (D[k - 1] >> 16) | (D[k] << 16);
      acc[2 * k] += bclo(Ek) * am;  acc[2 * k + 1] += bchi(Ek) * am;
    }
  }
  if (w < 95) { // dj = +1: shorts [l0+1 .. l0+16] of row q+1; elem15 may be chunk c0+1
    float a15 = ((l0 & 255) == 240 && c0 < 8) ? alpha[(c0 + 1) * 9216 + q + 1] : ap;
    unsigned D[9] = { Pa[0], Pa[1], Pa[2], Pa[3], Pb[0], Pb[1], Pb[2], Pb[3], Nw };
    unsigned F7 = (D[7] >> 16) | (D[8] << 16);
    if (lw0 == 32) F7 &= 0x0000FFFFu;    // elem15 would wrap to next lh row
#pragma unroll
    for (int k = 0; k < 7; k++) {
      unsigned Fk = (D[k] >> 16) | (D[k + 1] << 16);
      acc[2 * k] += bclo(Fk) * ap;  acc[2 * k + 1] += bchi(Fk) * ap;
    }
    acc[14] += bclo(F7) * ap;  acc[15] += bchi(F7) * a15;
  }

  short8 o0, o1;
#pragma unroll
  for (int k = 0; k < 8; k++) { o0[k] = f2s(acc[k]); o1[k] = f2s(acc[8 + k]); }
  short* dst = (short*)T + (size_t)qrel * 2304 + l0;
  *(short8*)dst = o0;
  *(short8*)(dst + 8) = o1;
}

// ---- stage 4: PV GEMM with FUSED coarse (di) stencil pass, NO ATOMICS --------------
// A-operand built in-register from T: 3 aligned 16B taps (c, ±(96 rows, 48 cols)) +
// guarded f32 adds in a2u's exact u order + same f2s -> bit-identical MFMA inputs.
// XCD-chunked q mapping. Store-side de-atomicized (round 19): each (y,z) writes its
// partial to a private P[y][z][o][q] f32 slab with plain float4 stores; k_comb
// folds partials + residual. y=2 k-split KEPT (round 20 showed halving the
// independent chains per q-tile costs more than the Ppart round-trip saves).
// block = 16q x 64o; blockIdx.y = k-half; 4 waves each own 288 of the half's 1152,
// LDS reduction. blockIdx.z = sample-within-batch.
__global__ __launch_bounds__(256) void k_pv3(
    const bf16* __restrict__ T, const bf16* __restrict__ Bb,
    float* __restrict__ Ppart, int nbase, int q0base, int qlo,
    int Bz, int psplit)
{
  __shared__ float Cred[4][16][67];
  int z = blockIdx.z;
  int n = nbase + z;
  T += (size_t)z * 9216 * 2304;
  int bpx = gridDim.x >> 3;
  int nb = (blockIdx.x & 7) * bpx + (blockIdx.x >> 3);   // XCD-chunked q mapping
  int tid = threadIdx.x, lane = tid & 63, wv = tid >> 6;
  int quad = lane >> 4, m16 = lane & 15;
  int qb = nb * 16;
  int kbase = blockIdx.y * 1152 + wv * 288;
  int q = q0base + qb + m16;          // absolute query row this lane owns
  int h = q / 96;
  const short* Trow = (const short*)T + (size_t)(q - qlo) * 2304;
  const short* Bp = (const short*)Bb + (size_t)n * 64 * 2304 + kbase;
  f32x4 acc[4];
#pragma unroll
  for (int t = 0; t < 4; t++) acc[t] = (f32x4){0.f, 0.f, 0.f, 0.f};

  // depth-1 double-buffered taps + B fragments ([2] arrays, static indexing)
  uint4v Ct[2], Nt[2], Pt[2];
  short8 bt[2][4];
  {
    const short* tc0 = Trow + kbase + quad * 8;
    Ct[0] = *(const uint4v*)(tc0);
    Nt[0] = *(const uint4v*)(tc0 - (size_t)96 * 2304 - 48);
    Pt[0] = *(const uint4v*)(tc0 + (size_t)96 * 2304 + 48);
#pragma unroll
    for (int ni = 0; ni < 4; ni++)
      bt[0][ni] = *(const short8*)&Bp[(size_t)(ni * 16 + m16) * 2304 + quad * 8];
  }

#pragma unroll
  for (int it = 0; it < 9; it++) {
    int cur = it & 1, nxt = cur ^ 1;
    if (it < 8) {                      // issue next iteration's loads first
      int kw1 = (it + 1) * 32;
      const short* tc1 = Trow + kbase + kw1 + quad * 8;
      Ct[nxt] = *(const uint4v*)(tc1);
      Nt[nxt] = *(const uint4v*)(tc1 - (size_t)96 * 2304 - 48);
      Pt[nxt] = *(const uint4v*)(tc1 + (size_t)96 * 2304 + 48);
#pragma unroll
      for (int ni = 0; ni < 4; ni++)
        bt[nxt][ni] = *(const short8*)&Bp[(size_t)(ni * 16 + m16) * 2304 + kw1 + quad * 8];
    }
    int labs = kbase + it * 32 + quad * 8;  // absolute l of this lane's 8-col A group
    int lh = labs / 48;                     // 0..47
    float s[8];
#pragma unroll
    for (int k = 0; k < 8; k++) s[k] = 0.f;
    if (h > 0 && lh > 0) {             // u = -1
#pragma unroll
      for (int k = 0; k < 4; k++) { s[2 * k] += bclo(Nt[cur][k]); s[2 * k + 1] += bchi(Nt[cur][k]); }
    }
    {                                  // u = 0
#pragma unroll
      for (int k = 0; k < 4; k++) { s[2 * k] += bclo(Ct[cur][k]); s[2 * k + 1] += bchi(Ct[cur][k]); }
    }
    if (h < 95 && lh < 47) {           // u = +1
#pragma unroll
      for (int k = 0; k < 4; k++) { s[2 * k] += bclo(Pt[cur][k]); s[2 * k + 1] += bchi(Pt[cur][k]); }
    }
    short8 a;
#pragma unroll
    for (int k = 0; k < 8; k++) a[k] = f2s(s[k]);
#pragma unroll
    for (int ni = 0; ni < 4; ni++)
      acc[ni] = __builtin_amdgcn_mfma_f32_16x16x32_bf16(a, bt[cur][ni], acc[ni], 0, 0, 0);
  }
#pragma unroll
  for (int ni = 0; ni < 4; ni++)
#pragma unroll
    for (int r = 0; r < 4; r++)
      Cred[wv][quad * 4 + r][ni * 16 + m16] = acc[ni][r];
  __syncthreads();
  {
    int o = tid >> 2;                // 0..63
    int qg = (tid & 3) * 4;          // 0..12
    size_t pid = ((size_t)(blockIdx.y * Bz + z) * 64 + o) * psplit + qb + qg;
    float4v st;
#pragma unroll
    for (int j = 0; j < 4; j++)
      st[j] = Cred[0][qg + j][o] + Cred[1][qg + j][o] + Cred[2][qg + j][o] + Cred[3][qg + j][o];
    *(float4v*)&Ppart[pid] = st;
  }
}

// ---- stage 5: combine partials + residual: out = inl + 0.25*(P0 + P1) --------------
// Plain streaming pass; replaces k_resid and all atomics. Grid covers Bz samples'
// (64 x psplit) f32 elements in float4 units.
__global__ __launch_bounds__(256) void k_comb(
    const float* __restrict__ Ppart, const float* __restrict__ inl,
    float* __restrict__ out, int nbase, int q0base, int psplit, int Bz)
{
  int i = blockIdx.x * 256 + threadIdx.x;
  int p4 = psplit >> 2;               // float4s per o-row
  int per = 64 * p4;                  // float4s per sample slab
  if (i >= Bz * per) return;
  int z = i / per, r = i - z * per;
  int o = r / p4, qr = r - o * p4;
  float4v p0 = ((const float4v*)Ppart)[(size_t)(0 * Bz + z) * per + r];
  float4v p1 = ((const float4v*)Ppart)[(size_t)(1 * Bz + z) * per + r];
  size_t oid4 = (size_t)(nbase + z) * 64 * 2304 + (size_t)o * 2304 + (q0base >> 2) + qr;
  float4v rv = ((const float4v*)inl)[oid4];
  float4v y;
#pragma unroll
  for (int j = 0; j < 4; j++) y[j] = rv[j] + 0.25f * p0[j] + 0.25f * p1[j];
  ((float4v*)out)[oid4] = y;
}

extern "C" void kernel_launch(void* const* d_in, const int* in_sizes, int n_in,
                              void* d_out, int out_size, void* d_ws, size_t ws_size,
                              hipStream_t stream)
{
  (void)in_sizes; (void)n_in; (void)out_size;
  const float* input_l = (const float*)d_in[0];
  const float* input_s = (const float*)d_in[1];
  const float* w_mlb = (const float*)d_in[2];
  const float* b_mlb = (const float*)d_in[3];
  const float* a_mlb = (const float*)d_in[4];
  const float* w_m   = (const float*)d_in[5];
  const float* b_m   = (const float*)d_in[6];
  const float* a_m   = (const float*)d_in[7];
  const float* w_asm = (const float*)d_in[8];
  const float* b_asm = (const float*)d_in[9];
  const float* a_asm = (const float*)d_in[10];
  float* out = (float*)d_out;

  char* base = (char*)d_ws;
  size_t off = 0;
  auto carve = [&](size_t bytes) -> char* {
    char* r = base + off;
    off += (bytes + 255) & ~(size_t)255;
    return r;
  };

  float* MBpad   = (float*)carve((size_t)4 * 32 * 98 * 98 * 4);
  float* REFpad  = (float*)carve((size_t)4 * 32 * 50 * 50 * 4);
  float* BASEpad = (float*)carve((size_t)4 * 64 * 50 * 50 * 4);
  bf16*  Kp      = (bf16*)carve((size_t)4 * 2304 * 320 * 2);
  bf16*  Xp      = (bf16*)carve((size_t)4 * 9216 * 320 * 2);
  bf16*  Bb      = (bf16*)carve((size_t)4 * 64 * 2304 * 2);
  float* statsM  = (float*)carve((size_t)2 * 9 * 9216 * 4);   // x2 for paired batch
  float* statsZ  = (float*)carve((size_t)2 * 9 * 9216 * 4);
  float* alpha   = (float*)carve((size_t)2 * 9 * 9216 * 4);
  size_t fixedOff = off;

  auto need = [&](int qmax, int psplit, int B) -> size_t {
    size_t a = (((size_t)qmax * 2304 * 2) * B + 255) & ~(size_t)255;
    size_t pp = ((size_t)2 * B * 64 * psplit * 4 + 255) & ~(size_t)255;
    return fixedOff + 2 * a + pp;   // attnT + T + partials
  };
  int nsplit, qmax, psplit, batchB;
  if (need(9216, 9216, 2) <= ws_size)      { batchB = 2; nsplit = 1; qmax = 9216; psplit = 9216; }
  else if (need(9216, 9216, 1) <= ws_size) { batchB = 1; nsplit = 1; qmax = 9216; psplit = 9216; }
  else if (need(5120, 4608, 1) <= ws_size) { batchB = 1; nsplit = 2; qmax = 5120; psplit = 4608; }
  else                                     { batchB = 1; nsplit = 4; qmax = 2816; psplit = 2304; }

  bf16*  attnT = (bf16*)carve((size_t)qmax * 2304 * 2 * batchB);
  bf16*  Tbuf  = (bf16*)carve((size_t)qmax * 2304 * 2 * batchB);
  float* Ppart = (float*)carve((size_t)2 * batchB * 64 * psplit * 4);

  // ---- prep (all samples, 2 dispatches) ----
  {
    int t1 = 4 * 32 * 98 * 98;
    int t2 = 4 * 32 * 50 * 50;
    int t3 = 4 * 64 * 50 * 50;
    int tt = t1 + t2 + t3;
    k_conv_all<<<dim3((tt + 255) / 256), dim3(256), 0, stream>>>(
        input_l, input_s, w_mlb, b_mlb, a_mlb, w_m, b_m, a_m, w_asm, b_asm, a_asm,
        MBpad, REFpad, BASEpad, t1, t2, t3);
    k_gather_all<<<dim3(2304 + 5760 + 288), dim3(256), 0, stream>>>(
        MBpad, REFpad, BASEpad, Kp, Xp, Bb);
  }

  if (batchB == 2) {
    // ---- paired-sample batching ----
    for (int p = 0; p < 2; p++) {
      int nb = p * 2;
      k_qk<<<dim3(144, 9, 2), dim3(256), 0, stream>>>(Xp, Kp, attnT, statsM, statsZ, nb, 0);
      k_alpha<<<dim3(36, 2), dim3(256), 0, stream>>>(statsM, statsZ, alpha, 0, 9216);
      k_a2v<<<dim3(5184, 1, 2), dim3(256), 0, stream>>>(attnT, alpha, Tbuf, 0);
      k_pv3<<<dim3(576, 2, 2), dim3(256), 0, stream>>>(Tbuf, Bb, Ppart, nb, 0, 0, 2, 9216);
      k_comb<<<dim3(1152), dim3(256), 0, stream>>>(Ppart, input_l, out, nb, 0, 9216, 2);
    }
  } else {
    // ---- fallback: per (sample, query band), z = 0 everywhere ----
    for (int n = 0; n < 4; n++) {
      for (int s = 0; s < nsplit; s++) {
        int q0 = s * psplit;
        int qlo = q0 - 256; if (qlo < 0) qlo = 0;
        int qhi = q0 + psplit + 256; if (qhi > 9216) qhi = 9216;
        int qlen = qhi - qlo;  // multiple of 256 by construction
        k_qk<<<dim3(qlen / 64, 9, 1), dim3(256), 0, stream>>>(Xp, Kp, attnT, statsM, statsZ, n, qlo);
        k_alpha<<<dim3(qlen / 256, 1), dim3(256), 0, stream>>>(statsM, statsZ, alpha, qlo, qlen);
        k_a2v<<<dim3(qlen * 144 / 256, 1, 1), dim3(256), 0, stream>>>(attnT, alpha, Tbuf, qlo);
        k_pv3<<<dim3(psplit / 16, 2, 1), dim3(256), 0, stream>>>(Tbuf, Bb, Ppart, n, q0, qlo, 1, psplit);
        k_comb<<<dim3(64 * psplit / 4 / 256), dim3(256), 0, stream>>>(Ppart, input_l, out, n, q0, psplit, 1);
      }
    }
  }
}